// Round 16
// baseline (39.780 us; speedup 1.0000x reference)
//
#include <hip/hip_runtime.h>

#define IMG 256
#define FBIG 1e10f
#define EPSA 1e-8f
#define BPAD 1e-4f
#define NBKT 128
#define ZSCL 32.0f         // bucket = (int)(zmin*32), floor = q/32
#define ZMARG 1e-3f
#define NWV 8              // waves per block (tile)

// Full per-face record, 64B:
// a: x1,y1, y2-y1, x2-x1   (edge0) | b: x2,y2, y0-y2, x0-x2 | c: x0,y0, y1-y0, x1-x0
// d: z0,z1,z2, area(=denom)
struct __align__(16) FRec { float4 a, b, c, d; };
// Cull record, 8B: quantized-outward pixel bbox + exact zmin
struct __align__(8) CRec { unsigned int bb; float zmin; };
// 16B pair of cull records (vector load)
struct __align__(16) CPair { CRec c0, c1; };

// Precompute: slot = face index (no compaction, no global atomics, no pre-zeroing).
__global__ __launch_bounds__(256) void precompute_kernel(
    const float* __restrict__ verts, const int* __restrict__ faces,
    FRec* __restrict__ rec_u, CRec* __restrict__ crec_u, int* __restrict__ bkt_u,
    unsigned int* __restrict__ perblk_hist, int nblk, int V, int F)
{
#pragma clang fp contract(off)
    __shared__ unsigned int lhist[NBKT];
    const int tid = threadIdx.x;
    const int blk = blockIdx.x;
    const int b   = blockIdx.y;
    if (tid < NBKT) lhist[tid] = 0u;
    __syncthreads();

    const int f = blk * 256 + tid;
    if (f < F) {
        const float* vb = verts + (size_t)b * V * 3;
        const int i0 = faces[3*f+0], i1 = faces[3*f+1], i2 = faces[3*f+2];
        const float x0 = -vb[3*i0+0], y0 = -vb[3*i0+1], z0 = vb[3*i0+2];
        const float x1 = -vb[3*i1+0], y1 = -vb[3*i1+1], z1 = vb[3*i1+2];
        const float x2 = -vb[3*i2+0], y2 = -vb[3*i2+1], z2 = vb[3*i2+2];
        const float area = (x1 - x0) * (y2 - y0) - (y1 - y0) * (x2 - x0);
        const float zmax = fmaxf(fmaxf(z0, z1), z2);
        int packed = -1;
        if (area > EPSA && zmax >= 0.0f) {
            FRec r;
            r.a = make_float4(x1, y1, y2 - y1, x2 - x1);
            r.b = make_float4(x2, y2, y0 - y2, x0 - x2);
            r.c = make_float4(x0, y0, y1 - y0, x1 - x0);
            r.d = make_float4(z0, z1, z2, area);
            rec_u[(size_t)b * F + f] = r;
            const float xmn = fminf(fminf(x0, x1), x2) - BPAD;
            const float xmx = fmaxf(fmaxf(x0, x1), x2) + BPAD;
            const float ymn = fminf(fminf(y0, y1), y2) - BPAD;
            const float ymx = fmaxf(fmaxf(y0, y1), y2) + BPAD;
            int cmin = (int)floorf((1.0f - xmx) * 128.0f - 0.5f);
            int cmax = (int)ceilf ((1.0f - xmn) * 128.0f - 0.5f);
            int rmin = (int)floorf((1.0f - ymx) * 128.0f - 0.5f);
            int rmax = (int)ceilf ((1.0f - ymn) * 128.0f - 0.5f);
            cmin = min(max(cmin, 0), 255); cmax = min(max(cmax, 0), 255);
            rmin = min(max(rmin, 0), 255); rmax = min(max(rmax, 0), 255);
            CRec cr;
            cr.bb = (unsigned int)cmin | ((unsigned int)cmax << 8) |
                    ((unsigned int)rmin << 16) | ((unsigned int)rmax << 24);
            cr.zmin = fminf(fminf(z0, z1), z2);
            crec_u[(size_t)b * F + f] = cr;
            int q = (int)(cr.zmin * ZSCL);
            q = q < 0 ? 0 : (q > NBKT - 1 ? NBKT - 1 : q);
            const unsigned int rank = atomicAdd(&lhist[q], 1u);   // LDS only
            packed = (q << 20) | (int)rank;
        }
        bkt_u[(size_t)b * F + f] = packed;
    }
    __syncthreads();
    if (tid < NBKT) perblk_hist[((size_t)b * nblk + blk) * NBKT + tid] = lhist[tid];
}

// Scatter: rebuild global positions from per-block histograms (no atomics).
__global__ __launch_bounds__(256) void scatter_kernel(
    const FRec* __restrict__ rec_u, const CRec* __restrict__ crec_u,
    const int* __restrict__ bkt_u, const unsigned int* __restrict__ perblk_hist,
    unsigned int* __restrict__ cnt,
    FRec* __restrict__ rec_s, CRec* __restrict__ crec_s, int* __restrict__ fid_s,
    float* __restrict__ floor_s, int nblk, int F)
{
    __shared__ unsigned int s_ph[40 * NBKT];     // per-block hists (nblk <= 40)
    __shared__ unsigned int s_gex[NBKT];
    const int tid = threadIdx.x;
    const int blk = blockIdx.x;
    const int b   = blockIdx.y;

    for (int i = tid; i < nblk * NBKT; i += 256)
        s_ph[i] = perblk_hist[(size_t)b * nblk * NBKT + i];
    __syncthreads();
    if (tid < NBKT) {
        unsigned int tot = 0;
        for (int j = 0; j < nblk; ++j) tot += s_ph[j * NBKT + tid];
        s_gex[tid] = tot;
    }
    __syncthreads();
    for (int d = 1; d < NBKT; d <<= 1) {
        unsigned int v = 0;
        if (tid < NBKT && tid >= d) v = s_gex[tid - d];
        __syncthreads();
        if (tid < NBKT) s_gex[tid] += v;
        __syncthreads();
    }
    if (tid == 0) cnt[b] = s_gex[NBKT - 1];      // same value from every block: benign

    const int f = blk * 256 + tid;
    if (f >= F) return;
    const int packed = bkt_u[(size_t)b * F + f];
    if (packed < 0) return;
    const int q    = packed >> 20;
    const int rank = packed & 0xFFFFF;
    unsigned int pos = (q ? s_gex[q - 1] : 0u) + (unsigned int)rank;
    for (int j = 0; j < blk; ++j) pos += s_ph[j * NBKT + q];
    rec_s[(size_t)b * F + pos]   = rec_u[(size_t)b * F + f];
    crec_s[(size_t)b * F + pos]  = crec_u[(size_t)b * F + f];
    fid_s[(size_t)b * F + pos]   = f;
    floor_s[(size_t)b * F + pos] = (q == 0) ? -3e38f : (float)q * (1.0f / ZSCL);
}

#define RLF(x) __uint_as_float((unsigned int)__builtin_amdgcn_readlane(__float_as_uint(x), bit))
#define UAF(u) __uint_as_float(u)

// Wave64 max via DPP (no LDS): row_shr 1/2/4/8, bcast15, bcast31, readlane 63.
// old=x keeps own value where DPP source invalid -> result is exact wave max.
__device__ __forceinline__ float wave_max_dpp(float v) {
    int x = __float_as_int(v), y;
    y = __builtin_amdgcn_update_dpp(x, x, 0x111, 0xf, 0xf, false);
    x = __float_as_int(fmaxf(__int_as_float(x), __int_as_float(y)));
    y = __builtin_amdgcn_update_dpp(x, x, 0x112, 0xf, 0xf, false);
    x = __float_as_int(fmaxf(__int_as_float(x), __int_as_float(y)));
    y = __builtin_amdgcn_update_dpp(x, x, 0x114, 0xf, 0xf, false);
    x = __float_as_int(fmaxf(__int_as_float(x), __int_as_float(y)));
    y = __builtin_amdgcn_update_dpp(x, x, 0x118, 0xf, 0xf, false);
    x = __float_as_int(fmaxf(__int_as_float(x), __int_as_float(y)));
    y = __builtin_amdgcn_update_dpp(x, x, 0x142, 0xf, 0xf, false);
    x = __float_as_int(fmaxf(__int_as_float(x), __int_as_float(y)));
    y = __builtin_amdgcn_update_dpp(x, x, 0x143, 0xf, 0xf, false);
    x = __float_as_int(fmaxf(__int_as_float(x), __int_as_float(y)));
    return UAF((unsigned int)__builtin_amdgcn_readlane(x, 63));
}

// Block = one 16x8 tile; 8 waves slice z-sorted faces in 128-face chunks.
__global__ __launch_bounds__(512, 8) void raster_kernel(
    const FRec* __restrict__ rec, const CRec* __restrict__ crec,
    const int* __restrict__ fids,
    const float* __restrict__ zfloor, const unsigned int* __restrict__ cnt,
    const float* __restrict__ verts, const int* __restrict__ faces,
    float* __restrict__ out, int B, int V, int F)
{
#pragma clang fp contract(off)
    __shared__ unsigned int s_z[128];                 // per-pixel best z bits
    __shared__ unsigned long long s_m[NWV][128];      // per-wave (z,fid) for merge

    const int tid  = threadIdx.x;
    const int wv   = tid >> 6;
    const int lane = tid & 63;
    const int blk  = blockIdx.x;                      // 0..1023
    const int b    = blk >> 9;
    const int t    = blk & 511;                       // 16 tile-cols x 32 tile-rows
    const int tile_c = (t & 15) * 16;
    const int tile_r = (t >> 4) * 8;
    const int col  = tile_c + (lane & 15);
    const int row0 = tile_r + (lane >> 4) * 2;        // lane owns 2 rows
    const int px0  = (lane & 15) + 16 * ((lane >> 4) * 2);

    if (tid < 128) s_z[tid] = 0xFFFFFFFFu;
    __syncthreads();

    const float px = 1.0f - (2.0f * (float)col + 1.0f) / 256.0f;
    float py[2];
    py[0] = 1.0f - (2.0f * (float)(row0 + 0) + 1.0f) / 256.0f;
    py[1] = 1.0f - (2.0f * (float)(row0 + 1) + 1.0f) / 256.0f;

    const float px_hi = 1.0f - (2.0f * (float)tile_c + 1.0f) / 256.0f;
    const float px_lo = 1.0f - (2.0f * (float)(tile_c + 15) + 1.0f) / 256.0f;
    const float py_hi = 1.0f - (2.0f * (float)tile_r + 1.0f) / 256.0f;
    const float py_lo = 1.0f - (2.0f * (float)(tile_r + 7) + 1.0f) / 256.0f;

    const int n = (int)cnt[b];
    const FRec*  rbp = rec    + (size_t)b * F;
    const CRec*  crp = crec   + (size_t)b * F;
    const int*   fbp = fids   + (size_t)b * F;
    const float* flp = zfloor + (size_t)b * F;
    const int nch = (n + 127) >> 7;                   // 128-face chunks

    unsigned long long best[2] = { ~0ULL, ~0ULL };
    float badj[2] = { FBIG, FBIG };

    for (int c = wv; c < nch; c += NWV) {
        // ---- absorb cross-wave z state (stale-safe: monotone), once per chunk ----
        const unsigned int zs0 = s_z[px0], zs1 = s_z[px0 + 16];
        if (zs0 != 0xFFFFFFFFu) badj[0] = fminf(badj[0], UAF(zs0) * 1.00001f + 1e-4f);
        if (zs1 != 0xFFFFFFFFu) badj[1] = fminf(badj[1], UAF(zs1) * 1.00001f + 1e-4f);
        const float lme = fmaxf(zs0 == 0xFFFFFFFFu ? FBIG : UAF(zs0),
                                zs1 == 0xFFFFFFFFu ? FBIG : UAF(zs1));
        const float l = wave_max_dpp(lme);            // DPP reduce, no LDS
        if (flp[c << 7] - ZMARG > l) break;           // sorted floors: rest loses

        const int base = c << 7;
        // 16B pair load (alignment: even index * 8B); OOB lanes gated by val below
        const CPair cp = *(const CPair*)&crp[base + 2 * lane];

        bool imp[2] = { false, false };
        #pragma unroll
        for (int j = 0; j < 2; ++j) {
            const int i  = base + 2 * lane + j;
            const bool val = i < n;
            const CRec cr = j ? cp.c1 : cp.c0;
            bool ov = val && (cr.zmin - ZMARG <= l) &&
                      ((int)(cr.bb & 255u)         <= tile_c + 15) &&
                      ((int)((cr.bb >> 8)  & 255u) >= tile_c)      &&
                      ((int)((cr.bb >> 16) & 255u) <= tile_r + 7)  &&
                      ((int)((cr.bb >> 24) & 255u) >= tile_r);

            FRec r; int fid = 0;
            if (ov) {
                r = rbp[i]; fid = fbp[i];
                const float ea = (((r.a.z > 0.f) ? px_hi : px_lo) - r.a.x) * r.a.z
                               - (((r.a.w > 0.f) ? py_lo : py_hi) - r.a.y) * r.a.w;
                const float eb = (((r.b.z > 0.f) ? px_hi : px_lo) - r.b.x) * r.b.z
                               - (((r.b.w > 0.f) ? py_lo : py_hi) - r.b.y) * r.b.w;
                const float ec = (((r.c.z > 0.f) ? px_hi : px_lo) - r.c.x) * r.c.z
                               - (((r.c.w > 0.f) ? py_lo : py_hi) - r.c.y) * r.c.w;
                ov = (ea >= 0.f) && (eb >= 0.f) && (ec >= 0.f);
            }
            unsigned long long mask = __ballot(ov);
            while (mask) {
                const int bit = (int)__builtin_ctzll(mask);
                mask &= mask - 1;
                const float ax = RLF(r.a.x), ay = RLF(r.a.y), ady = RLF(r.a.z), adx = RLF(r.a.w);
                const float bx = RLF(r.b.x), by = RLF(r.b.y), bdy = RLF(r.b.z), bdx = RLF(r.b.w);
                const float cx = RLF(r.c.x), cy = RLF(r.c.y), cdy = RLF(r.c.z), cdx = RLF(r.c.w);
                const float z0 = RLF(r.d.x), z1 = RLF(r.d.y), z2 = RLF(r.d.z), area = RLF(r.d.w);
                const int   fs = __builtin_amdgcn_readlane(fid, bit);
                const float t0 = (px - ax) * ady;   // ref-identical shared terms
                const float t1 = (px - bx) * bdy;
                const float t2 = (px - cx) * cdy;
                #pragma unroll
                for (int k = 0; k < 2; ++k) {
                    const float e0 = t0 - (py[k] - ay) * adx;
                    const float e1 = t1 - (py[k] - by) * bdx;
                    const float e2 = t2 - (py[k] - cy) * cdx;
                    const float m  = fminf(fminf(e0, e1), e2);
                    const float zt = __builtin_fmaf(e2, z2, __builtin_fmaf(e1, z1, e0 * z0));
                    if (m >= 0.0f && zt >= -1e-4f && zt <= badj[k] * area) {
                        // exact path: bit-identical to reference
                        const float w0 = e0 / area;
                        const float w1 = e1 / area;
                        const float w2 = e2 / area;
                        const float pz = (w0 * z0 + w1 * z1) + w2 * z2;
                        if (pz >= 0.0f && pz < FBIG) {
                            const unsigned long long cand =
                                ((unsigned long long)__float_as_uint(pz + 0.0f) << 32) |
                                (unsigned int)fs;
                            if (cand < best[k]) {
                                best[k] = cand;
                                const float bz = UAF((unsigned int)(best[k] >> 32));
                                badj[k] = fminf(badj[k], bz * 1.00001f + 1e-4f);
                                imp[k] = true;
                            }
                        }
                    }
                }
            }
        }
        // ---- publish improved z to shared per-pixel state ----
        if (imp[0]) atomicMin(&s_z[px0],      (unsigned int)(best[0] >> 32));
        if (imp[1]) atomicMin(&s_z[px0 + 16], (unsigned int)(best[1] >> 32));
    }

    // ---- exact merge across the 8 waves, then inline resolve by wave 0 ----
    s_m[wv][px0]      = best[0];
    s_m[wv][px0 + 16] = best[1];
    __syncthreads();
    if (wv == 0) {
        #pragma unroll
        for (int k = 0; k < 2; ++k) {
            const int p = px0 + 16 * k;
            unsigned long long m = s_m[0][p];
            #pragma unroll
            for (int j = 1; j < NWV; ++j) m = s_m[j][p] < m ? s_m[j][p] : m;

            const int idx = (b * IMG + row0 + k) * IMG + col;
            float p2f = -1.0f, o0 = -1.0f, o1 = -1.0f, o2 = -1.0f;
            if (m != ~0ULL) {
                const int fidw = (int)(m & 0xFFFFFFFFu);
                const float* vb = verts + (size_t)b * V * 3;
                const int i0 = faces[3*fidw+0], i1 = faces[3*fidw+1], i2 = faces[3*fidw+2];
                const float x0 = -vb[3*i0+0], y0 = -vb[3*i0+1];
                const float x1 = -vb[3*i1+0], y1 = -vb[3*i1+1];
                const float x2 = -vb[3*i2+0], y2 = -vb[3*i2+1];
                const float area = (x1 - x0) * (y2 - y0) - (y1 - y0) * (x2 - x0);
                const float e0 = (px - x1) * (y2 - y1) - (py[k] - y1) * (x2 - x1);
                const float e1 = (px - x2) * (y0 - y2) - (py[k] - y2) * (x0 - x2);
                const float e2 = (px - x0) * (y1 - y0) - (py[k] - y0) * (x1 - x0);
                o0 = e0 / area; o1 = e1 / area; o2 = e2 / area;
                p2f = (float)(fidw + b * F);
            }
            out[idx] = p2f;
            const size_t boff = (size_t)B * IMG * IMG + (size_t)idx * 3;
            out[boff + 0] = o0; out[boff + 1] = o1; out[boff + 2] = o2;
        }
    }
}

extern "C" void kernel_launch(void* const* d_in, const int* in_sizes, int n_in,
                              void* d_out, int out_size, void* d_ws, size_t ws_size,
                              hipStream_t stream) {
    const float* vertices = (const float*)d_in[0];
    const int*   faces    = (const int*)d_in[1];
    float* out = (float*)d_out;

    const int F = in_sizes[1] / 3;
    const int B = 2;
    const int V = in_sizes[0] / (3 * B);
    const int nblk = (F + 255) / 256;     // 39 for F=9976 (scatter LDS supports <=40)

    char* w = (char*)d_ws;
    unsigned int* cnt = (unsigned int*)w;                        // [0..8)
    size_t off = 256;
    unsigned int* perblk_hist = (unsigned int*)(w + off);
    off += (size_t)B * nblk * NBKT * 4;
    off = (off + 255) & ~(size_t)255;
    FRec* rec_u  = (FRec*)(w + off);  off += (size_t)B * F * sizeof(FRec);
    CRec* crec_u = (CRec*)(w + off);  off += (size_t)B * F * sizeof(CRec);
    int*  bkt_u  = (int*)(w + off);   off += (size_t)B * F * 4;
    FRec* rec_s  = (FRec*)(w + off);  off += (size_t)B * F * sizeof(FRec);
    CRec* crec_s = (CRec*)(w + off);  off += (size_t)B * F * sizeof(CRec);
    int*  fid_s  = (int*)(w + off);   off += (size_t)B * F * 4;
    float* floor_s = (float*)(w + off);

    dim3 gpre(nblk, B);
    precompute_kernel<<<gpre, 256, 0, stream>>>(vertices, faces, rec_u, crec_u, bkt_u,
                                                perblk_hist, nblk, V, F);
    scatter_kernel<<<gpre, 256, 0, stream>>>(rec_u, crec_u, bkt_u, perblk_hist, cnt,
                                             rec_s, crec_s, fid_s, floor_s, nblk, F);

    raster_kernel<<<1024, 512, 0, stream>>>(rec_s, crec_s, fid_s, floor_s, cnt,
                                            vertices, faces, out, B, V, F);
}

// Round 17
// 36.563 us; speedup vs baseline: 1.0880x; 1.0880x over previous
//
#include <hip/hip_runtime.h>

#define IMG 256
#define FBIG 1e10f
#define EPSA 1e-8f
#define BPAD 1e-4f
#define NBKT 128
#define ZSCL 32.0f         // bucket = (int)(zmin*32), floor = q/32
#define ZMARG 1e-3f
#define NWV 8              // waves per block (tile)

// Full per-face record, 64B:
// a: x1,y1, y2-y1, x2-x1   (edge0) | b: x2,y2, y0-y2, x0-x2 | c: x0,y0, y1-y0, x1-x0
// d: z0,z1,z2, area(=denom)
struct __align__(16) FRec { float4 a, b, c, d; };
// Cull record, 8B: quantized-outward pixel bbox + exact zmin
struct __align__(8) CRec { unsigned int bb; float zmin; };

// Precompute: slot = face index (no compaction, no global atomics, no pre-zeroing).
__global__ __launch_bounds__(256) void precompute_kernel(
    const float* __restrict__ verts, const int* __restrict__ faces,
    FRec* __restrict__ rec_u, CRec* __restrict__ crec_u, int* __restrict__ bkt_u,
    unsigned int* __restrict__ perblk_hist, int nblk, int V, int F)
{
#pragma clang fp contract(off)
    __shared__ unsigned int lhist[NBKT];
    const int tid = threadIdx.x;
    const int blk = blockIdx.x;
    const int b   = blockIdx.y;
    if (tid < NBKT) lhist[tid] = 0u;
    __syncthreads();

    const int f = blk * 256 + tid;
    if (f < F) {
        const float* vb = verts + (size_t)b * V * 3;
        const int i0 = faces[3*f+0], i1 = faces[3*f+1], i2 = faces[3*f+2];
        const float x0 = -vb[3*i0+0], y0 = -vb[3*i0+1], z0 = vb[3*i0+2];
        const float x1 = -vb[3*i1+0], y1 = -vb[3*i1+1], z1 = vb[3*i1+2];
        const float x2 = -vb[3*i2+0], y2 = -vb[3*i2+1], z2 = vb[3*i2+2];
        const float area = (x1 - x0) * (y2 - y0) - (y1 - y0) * (x2 - x0);
        const float zmax = fmaxf(fmaxf(z0, z1), z2);
        int packed = -1;
        if (area > EPSA && zmax >= 0.0f) {
            FRec r;
            r.a = make_float4(x1, y1, y2 - y1, x2 - x1);
            r.b = make_float4(x2, y2, y0 - y2, x0 - x2);
            r.c = make_float4(x0, y0, y1 - y0, x1 - x0);
            r.d = make_float4(z0, z1, z2, area);
            rec_u[(size_t)b * F + f] = r;
            const float xmn = fminf(fminf(x0, x1), x2) - BPAD;
            const float xmx = fmaxf(fmaxf(x0, x1), x2) + BPAD;
            const float ymn = fminf(fminf(y0, y1), y2) - BPAD;
            const float ymx = fmaxf(fmaxf(y0, y1), y2) + BPAD;
            int cmin = (int)floorf((1.0f - xmx) * 128.0f - 0.5f);
            int cmax = (int)ceilf ((1.0f - xmn) * 128.0f - 0.5f);
            int rmin = (int)floorf((1.0f - ymx) * 128.0f - 0.5f);
            int rmax = (int)ceilf ((1.0f - ymn) * 128.0f - 0.5f);
            cmin = min(max(cmin, 0), 255); cmax = min(max(cmax, 0), 255);
            rmin = min(max(rmin, 0), 255); rmax = min(max(rmax, 0), 255);
            CRec cr;
            cr.bb = (unsigned int)cmin | ((unsigned int)cmax << 8) |
                    ((unsigned int)rmin << 16) | ((unsigned int)rmax << 24);
            cr.zmin = fminf(fminf(z0, z1), z2);
            crec_u[(size_t)b * F + f] = cr;
            int q = (int)(cr.zmin * ZSCL);
            q = q < 0 ? 0 : (q > NBKT - 1 ? NBKT - 1 : q);
            const unsigned int rank = atomicAdd(&lhist[q], 1u);   // LDS only
            packed = (q << 20) | (int)rank;
        }
        bkt_u[(size_t)b * F + f] = packed;
    }
    __syncthreads();
    if (tid < NBKT) perblk_hist[((size_t)b * nblk + blk) * NBKT + tid] = lhist[tid];
}

// Scatter: rebuild global positions from per-block histograms (no atomics).
__global__ __launch_bounds__(256) void scatter_kernel(
    const FRec* __restrict__ rec_u, const CRec* __restrict__ crec_u,
    const int* __restrict__ bkt_u, const unsigned int* __restrict__ perblk_hist,
    unsigned int* __restrict__ cnt,
    FRec* __restrict__ rec_s, CRec* __restrict__ crec_s, int* __restrict__ fid_s,
    float* __restrict__ floor_s, int nblk, int F)
{
    __shared__ unsigned int s_ph[40 * NBKT];     // per-block hists (nblk <= 40)
    __shared__ unsigned int s_gex[NBKT];
    const int tid = threadIdx.x;
    const int blk = blockIdx.x;
    const int b   = blockIdx.y;

    for (int i = tid; i < nblk * NBKT; i += 256)
        s_ph[i] = perblk_hist[(size_t)b * nblk * NBKT + i];
    __syncthreads();
    if (tid < NBKT) {
        unsigned int tot = 0;
        for (int j = 0; j < nblk; ++j) tot += s_ph[j * NBKT + tid];
        s_gex[tid] = tot;
    }
    __syncthreads();
    for (int d = 1; d < NBKT; d <<= 1) {
        unsigned int v = 0;
        if (tid < NBKT && tid >= d) v = s_gex[tid - d];
        __syncthreads();
        if (tid < NBKT) s_gex[tid] += v;
        __syncthreads();
    }
    if (tid == 0) cnt[b] = s_gex[NBKT - 1];      // same value from every block: benign

    const int f = blk * 256 + tid;
    if (f >= F) return;
    const int packed = bkt_u[(size_t)b * F + f];
    if (packed < 0) return;
    const int q    = packed >> 20;
    const int rank = packed & 0xFFFFF;
    unsigned int pos = (q ? s_gex[q - 1] : 0u) + (unsigned int)rank;
    for (int j = 0; j < blk; ++j) pos += s_ph[j * NBKT + q];
    rec_s[(size_t)b * F + pos]   = rec_u[(size_t)b * F + f];
    crec_s[(size_t)b * F + pos]  = crec_u[(size_t)b * F + f];
    fid_s[(size_t)b * F + pos]   = f;
    floor_s[(size_t)b * F + pos] = (q == 0) ? -3e38f : (float)q * (1.0f / ZSCL);
}

#define RLF(x) __uint_as_float((unsigned int)__builtin_amdgcn_readlane(__float_as_uint(x), bit))
#define UAF(u) __uint_as_float(u)

// Wave64 max via DPP (no LDS): row_shr 1/2/4/8, bcast15, bcast31, readlane 63.
// old=x keeps own value where DPP source invalid -> result is exact wave max.
__device__ __forceinline__ float wave_max_dpp(float v) {
    int x = __float_as_int(v), y;
    y = __builtin_amdgcn_update_dpp(x, x, 0x111, 0xf, 0xf, false);
    x = __float_as_int(fmaxf(__int_as_float(x), __int_as_float(y)));
    y = __builtin_amdgcn_update_dpp(x, x, 0x112, 0xf, 0xf, false);
    x = __float_as_int(fmaxf(__int_as_float(x), __int_as_float(y)));
    y = __builtin_amdgcn_update_dpp(x, x, 0x114, 0xf, 0xf, false);
    x = __float_as_int(fmaxf(__int_as_float(x), __int_as_float(y)));
    y = __builtin_amdgcn_update_dpp(x, x, 0x118, 0xf, 0xf, false);
    x = __float_as_int(fmaxf(__int_as_float(x), __int_as_float(y)));
    y = __builtin_amdgcn_update_dpp(x, x, 0x142, 0xf, 0xf, false);
    x = __float_as_int(fmaxf(__int_as_float(x), __int_as_float(y)));
    y = __builtin_amdgcn_update_dpp(x, x, 0x143, 0xf, 0xf, false);
    x = __float_as_int(fmaxf(__int_as_float(x), __int_as_float(y)));
    return UAF((unsigned int)__builtin_amdgcn_readlane(x, 63));
}

// Block = one 16x8 tile; 8 waves slice the z-sorted face list round-robin.
// Two-level cull: 8B CRec (int bbox + zmin) -> survivors load 64B FRec.  (R15 body)
__global__ __launch_bounds__(512, 8) void raster_kernel(
    const FRec* __restrict__ rec, const CRec* __restrict__ crec,
    const int* __restrict__ fids,
    const float* __restrict__ zfloor, const unsigned int* __restrict__ cnt,
    const float* __restrict__ verts, const int* __restrict__ faces,
    float* __restrict__ out, int B, int V, int F)
{
#pragma clang fp contract(off)
    __shared__ unsigned int s_z[128];                 // per-pixel best z bits
    __shared__ unsigned long long s_m[NWV][128];      // per-wave (z,fid) for merge

    const int tid  = threadIdx.x;
    const int wv   = tid >> 6;
    const int lane = tid & 63;
    const int blk  = blockIdx.x;                      // 0..1023
    const int b    = blk >> 9;
    const int t    = blk & 511;                       // 16 tile-cols x 32 tile-rows
    const int tile_c = (t & 15) * 16;
    const int tile_r = (t >> 4) * 8;
    const int col  = tile_c + (lane & 15);
    const int row0 = tile_r + (lane >> 4) * 2;        // lane owns 2 rows
    const int px0  = (lane & 15) + 16 * ((lane >> 4) * 2);

    if (tid < 128) s_z[tid] = 0xFFFFFFFFu;
    __syncthreads();

    const float px = 1.0f - (2.0f * (float)col + 1.0f) / 256.0f;
    float py[2];
    py[0] = 1.0f - (2.0f * (float)(row0 + 0) + 1.0f) / 256.0f;
    py[1] = 1.0f - (2.0f * (float)(row0 + 1) + 1.0f) / 256.0f;

    const float px_hi = 1.0f - (2.0f * (float)tile_c + 1.0f) / 256.0f;
    const float px_lo = 1.0f - (2.0f * (float)(tile_c + 15) + 1.0f) / 256.0f;
    const float py_hi = 1.0f - (2.0f * (float)tile_r + 1.0f) / 256.0f;
    const float py_lo = 1.0f - (2.0f * (float)(tile_r + 7) + 1.0f) / 256.0f;

    const int n = (int)cnt[b];
    const FRec*  rbp = rec    + (size_t)b * F;
    const CRec*  crp = crec   + (size_t)b * F;
    const int*   fbp = fids   + (size_t)b * F;
    const float* flp = zfloor + (size_t)b * F;
    const int ngroups = (n + 63) >> 6;

    unsigned long long best[2] = { ~0ULL, ~0ULL };
    float badj[2] = { FBIG, FBIG };

    for (int g = wv; g < ngroups; g += NWV) {
        // ---- absorb cross-wave z state (stale-safe: monotone) ----
        const unsigned int zs0 = s_z[px0], zs1 = s_z[px0 + 16];
        if (zs0 != 0xFFFFFFFFu) badj[0] = fminf(badj[0], UAF(zs0) * 1.00001f + 1e-4f);
        if (zs1 != 0xFFFFFFFFu) badj[1] = fminf(badj[1], UAF(zs1) * 1.00001f + 1e-4f);
        const float lme = fmaxf(zs0 == 0xFFFFFFFFu ? FBIG : UAF(zs0),
                                zs1 == 0xFFFFFFFFu ? FBIG : UAF(zs1));
        const float l = wave_max_dpp(lme);      // DPP reduce (VALU), no LDS
        if (flp[g << 6] - ZMARG > l) break;     // sorted floors: rest of slice loses

        // ---- level-1 cull: 8B record (int bbox + zmin) ----
        const int i  = (g << 6) + lane;
        const bool val = i < n;
        const int ic = val ? i : (n - 1);
        const CRec cr = crp[ic];
        bool ov = val && (cr.zmin - ZMARG <= l) &&
                  ((int)(cr.bb & 255u)         <= tile_c + 15) &&
                  ((int)((cr.bb >> 8)  & 255u) >= tile_c)      &&
                  ((int)((cr.bb >> 16) & 255u) <= tile_r + 7)  &&
                  ((int)((cr.bb >> 24) & 255u) >= tile_r);

        // ---- level-2: survivors load full record + exact rect-max edge test ----
        FRec r; int fid = 0;
        if (ov) {
            r = rbp[ic]; fid = fbp[ic];
            const float ea = (((r.a.z > 0.f) ? px_hi : px_lo) - r.a.x) * r.a.z
                           - (((r.a.w > 0.f) ? py_lo : py_hi) - r.a.y) * r.a.w;
            const float eb = (((r.b.z > 0.f) ? px_hi : px_lo) - r.b.x) * r.b.z
                           - (((r.b.w > 0.f) ? py_lo : py_hi) - r.b.y) * r.b.w;
            const float ec = (((r.c.z > 0.f) ? px_hi : px_lo) - r.c.x) * r.c.z
                           - (((r.c.w > 0.f) ? py_lo : py_hi) - r.c.y) * r.c.w;
            ov = (ea >= 0.f) && (eb >= 0.f) && (ec >= 0.f);
        }
        bool imp[2] = { false, false };
        unsigned long long mask = __ballot(ov);
        while (mask) {
            const int bit = (int)__builtin_ctzll(mask);
            mask &= mask - 1;
            const float ax = RLF(r.a.x), ay = RLF(r.a.y), ady = RLF(r.a.z), adx = RLF(r.a.w);
            const float bx = RLF(r.b.x), by = RLF(r.b.y), bdy = RLF(r.b.z), bdx = RLF(r.b.w);
            const float cx = RLF(r.c.x), cy = RLF(r.c.y), cdy = RLF(r.c.z), cdx = RLF(r.c.w);
            const float z0 = RLF(r.d.x), z1 = RLF(r.d.y), z2 = RLF(r.d.z), area = RLF(r.d.w);
            const int   fs = __builtin_amdgcn_readlane(fid, bit);
            const float t0 = (px - ax) * ady;   // ref-identical shared terms
            const float t1 = (px - bx) * bdy;
            const float t2 = (px - cx) * cdy;
            #pragma unroll
            for (int k = 0; k < 2; ++k) {
                const float e0 = t0 - (py[k] - ay) * adx;
                const float e1 = t1 - (py[k] - by) * bdx;
                const float e2 = t2 - (py[k] - cy) * cdx;
                const float m  = fminf(fminf(e0, e1), e2);
                const float zt = __builtin_fmaf(e2, z2, __builtin_fmaf(e1, z1, e0 * z0));
                if (m >= 0.0f && zt >= -1e-4f && zt <= badj[k] * area) {
                    // exact path: bit-identical to reference
                    const float w0 = e0 / area;
                    const float w1 = e1 / area;
                    const float w2 = e2 / area;
                    const float pz = (w0 * z0 + w1 * z1) + w2 * z2;
                    if (pz >= 0.0f && pz < FBIG) {
                        const unsigned long long cand =
                            ((unsigned long long)__float_as_uint(pz + 0.0f) << 32) |
                            (unsigned int)fs;
                        if (cand < best[k]) {
                            best[k] = cand;
                            const float bz = UAF((unsigned int)(best[k] >> 32));
                            badj[k] = fminf(badj[k], bz * 1.00001f + 1e-4f);
                            imp[k] = true;
                        }
                    }
                }
            }
        }
        // ---- publish improved z to shared per-pixel state ----
        if (imp[0]) atomicMin(&s_z[px0],      (unsigned int)(best[0] >> 32));
        if (imp[1]) atomicMin(&s_z[px0 + 16], (unsigned int)(best[1] >> 32));
    }

    // ---- exact merge across the 8 waves, then inline resolve by wave 0 ----
    s_m[wv][px0]      = best[0];
    s_m[wv][px0 + 16] = best[1];
    __syncthreads();
    if (wv == 0) {
        #pragma unroll
        for (int k = 0; k < 2; ++k) {
            const int p = px0 + 16 * k;
            unsigned long long m = s_m[0][p];
            #pragma unroll
            for (int j = 1; j < NWV; ++j) m = s_m[j][p] < m ? s_m[j][p] : m;

            const int idx = (b * IMG + row0 + k) * IMG + col;
            float p2f = -1.0f, o0 = -1.0f, o1 = -1.0f, o2 = -1.0f;
            if (m != ~0ULL) {
                const int fidw = (int)(m & 0xFFFFFFFFu);
                const float* vb = verts + (size_t)b * V * 3;
                const int i0 = faces[3*fidw+0], i1 = faces[3*fidw+1], i2 = faces[3*fidw+2];
                const float x0 = -vb[3*i0+0], y0 = -vb[3*i0+1];
                const float x1 = -vb[3*i1+0], y1 = -vb[3*i1+1];
                const float x2 = -vb[3*i2+0], y2 = -vb[3*i2+1];
                const float area = (x1 - x0) * (y2 - y0) - (y1 - y0) * (x2 - x0);
                const float e0 = (px - x1) * (y2 - y1) - (py[k] - y1) * (x2 - x1);
                const float e1 = (px - x2) * (y0 - y2) - (py[k] - y2) * (x0 - x2);
                const float e2 = (px - x0) * (y1 - y0) - (py[k] - y0) * (x1 - x0);
                o0 = e0 / area; o1 = e1 / area; o2 = e2 / area;
                p2f = (float)(fidw + b * F);
            }
            out[idx] = p2f;
            const size_t boff = (size_t)B * IMG * IMG + (size_t)idx * 3;
            out[boff + 0] = o0; out[boff + 1] = o1; out[boff + 2] = o2;
        }
    }
}

extern "C" void kernel_launch(void* const* d_in, const int* in_sizes, int n_in,
                              void* d_out, int out_size, void* d_ws, size_t ws_size,
                              hipStream_t stream) {
    const float* vertices = (const float*)d_in[0];
    const int*   faces    = (const int*)d_in[1];
    float* out = (float*)d_out;

    const int F = in_sizes[1] / 3;
    const int B = 2;
    const int V = in_sizes[0] / (3 * B);
    const int nblk = (F + 255) / 256;     // 39 for F=9976 (scatter LDS supports <=40)

    char* w = (char*)d_ws;
    unsigned int* cnt = (unsigned int*)w;                        // [0..8)
    size_t off = 256;
    unsigned int* perblk_hist = (unsigned int*)(w + off);
    off += (size_t)B * nblk * NBKT * 4;
    off = (off + 255) & ~(size_t)255;
    FRec* rec_u  = (FRec*)(w + off);  off += (size_t)B * F * sizeof(FRec);
    CRec* crec_u = (CRec*)(w + off);  off += (size_t)B * F * sizeof(CRec);
    int*  bkt_u  = (int*)(w + off);   off += (size_t)B * F * 4;
    FRec* rec_s  = (FRec*)(w + off);  off += (size_t)B * F * sizeof(FRec);
    CRec* crec_s = (CRec*)(w + off);  off += (size_t)B * F * sizeof(CRec);
    int*  fid_s  = (int*)(w + off);   off += (size_t)B * F * 4;
    float* floor_s = (float*)(w + off);

    dim3 gpre(nblk, B);
    precompute_kernel<<<gpre, 256, 0, stream>>>(vertices, faces, rec_u, crec_u, bkt_u,
                                                perblk_hist, nblk, V, F);
    scatter_kernel<<<gpre, 256, 0, stream>>>(rec_u, crec_u, bkt_u, perblk_hist, cnt,
                                             rec_s, crec_s, fid_s, floor_s, nblk, F);

    raster_kernel<<<1024, 512, 0, stream>>>(rec_s, crec_s, fid_s, floor_s, cnt,
                                            vertices, faces, out, B, V, F);
}